// Round 1
// baseline (180.673 us; speedup 1.0000x reference)
//
#include <hip/hip_runtime.h>
#include <stdint.h>

typedef __attribute__((ext_vector_type(8))) short s8v;
typedef __attribute__((ext_vector_type(4))) short s4v;
typedef __attribute__((ext_vector_type(4))) float f4v;

#define D_DIM 1024
#define H_NUM 16
#define HD 64
#define SEQ 2048
#define BSZ 2
#define MROWS (BSZ * SEQ)   // 4096

__device__ __forceinline__ unsigned short f2bf(float f) {
  unsigned u = __builtin_bit_cast(unsigned, f);
  u += 0x7fffu + ((u >> 16) & 1u);
  return (unsigned short)(u >> 16);
}

__device__ __forceinline__ void async16(const unsigned short* g, unsigned short* l) {
  __builtin_amdgcn_global_load_lds(
      (__attribute__((address_space(1))) unsigned int*)(uintptr_t)g,
      (__attribute__((address_space(3))) unsigned int*)l, 16, 0, 0);
}

__device__ __forceinline__ f4v mfma16(s8v a, s8v b, f4v c) {
  return __builtin_amdgcn_mfma_f32_16x16x32_bf16(a, b, c, 0, 0, 0);
}

// ---------------- fp32 -> bf16 convert ----------------
__global__ __launch_bounds__(256) void cvt_bf16(const float* __restrict__ src,
                                                unsigned short* __restrict__ dst,
                                                int n4) {
  int i = blockIdx.x * blockDim.x + threadIdx.x;
  int stride = gridDim.x * blockDim.x;
  for (; i < n4; i += stride) {
    f4v v = *(const f4v*)(src + i * 4);
    s4v o;
    o[0] = (short)f2bf(v[0]);
    o[1] = (short)f2bf(v[1]);
    o[2] = (short)f2bf(v[2]);
    o[3] = (short)f2bf(v[3]);
    *(s4v*)(dst + i * 4) = o;
  }
}

// ---------------- QKV projection GEMM ----------------
// Y[M=4096][N=1024] = Xb[M][K=1024] * W[N][K]^T + bias
// z=0 -> qb [b][h][s][hd], z=1 -> kb same, z=2 -> vt [b][h][hd][s]
__global__ __launch_bounds__(256) void qkv_gemm(
    const unsigned short* __restrict__ Xb, const unsigned short* __restrict__ Wb,
    const float* __restrict__ bq, const float* __restrict__ bk,
    const float* __restrict__ bv, unsigned short* __restrict__ qb,
    unsigned short* __restrict__ kb, unsigned short* __restrict__ vt) {
  __shared__ __align__(16) unsigned short At[128 * 64];
  __shared__ __align__(16) unsigned short Bt[128 * 64];

  const int z = blockIdx.z;
  const unsigned short* W = Wb + z * (D_DIM * D_DIM);
  const float* bias = (z == 0) ? bq : ((z == 1) ? bk : bv);
  const int row0 = blockIdx.x * 128;
  const int col0 = blockIdx.y * 128;
  const int t = threadIdx.x;
  const int w = t >> 6, l = t & 63;
  const int wr = w >> 1, wc = w & 1;
  const int lg = l >> 4, lc = l & 15;

  f4v acc[4][4];
#pragma unroll
  for (int m = 0; m < 4; ++m)
#pragma unroll
    for (int n = 0; n < 4; ++n) acc[m][n] = (f4v){0.f, 0.f, 0.f, 0.f};

  const int sr = t >> 3;          // staging row sub-index
  const int sc = (t & 7) * 8;     // staging col (elements)
  const int arow = wr * 64 + lc;
  const int brow = wc * 64 + lc;
  const int koff = 8 * lg;

  for (int it = 0; it < 16; ++it) {
    const int k0 = it * 64;
    __syncthreads();
#pragma unroll
    for (int i = 0; i < 4; ++i) {
      async16(Xb + (size_t)(row0 + i * 32 + sr) * D_DIM + k0 + sc, At + i * 2048 + t * 8);
      async16(W + (size_t)(col0 + i * 32 + sr) * D_DIM + k0 + sc, Bt + i * 2048 + t * 8);
    }
    __syncthreads();
#pragma unroll
    for (int kc = 0; kc < 2; ++kc) {
      s8v a[4], b[4];
#pragma unroll
      for (int m = 0; m < 4; ++m)
        a[m] = *(const s8v*)(At + (arow + m * 16) * 64 + kc * 32 + koff);
#pragma unroll
      for (int n = 0; n < 4; ++n)
        b[n] = *(const s8v*)(Bt + (brow + n * 16) * 64 + kc * 32 + koff);
#pragma unroll
      for (int m = 0; m < 4; ++m)
#pragma unroll
        for (int n = 0; n < 4; ++n) acc[m][n] = mfma16(a[m], b[n], acc[m][n]);
    }
  }

  // epilogue
#pragma unroll
  for (int m = 0; m < 4; ++m) {
    const int sg0 = row0 + wr * 64 + m * 16 + 4 * lg;  // global row (4 consecutive via regs)
    const int b = sg0 >> 11;
    const int sl0 = sg0 & (SEQ - 1);
#pragma unroll
    for (int n = 0; n < 4; ++n) {
      const int j = col0 + wc * 64 + n * 16 + lc;  // output col
      const int h = j >> 6, hd = j & 63;
      const float bs = bias[j];
      if (z == 2) {
        s4v o;
#pragma unroll
        for (int r = 0; r < 4; ++r) o[r] = (short)f2bf(acc[m][n][r] + bs);
        *(s4v*)(vt + ((size_t)(b * H_NUM + h) * HD + hd) * SEQ + sl0) = o;
      } else {
        unsigned short* dst = (z == 0) ? qb : kb;
#pragma unroll
        for (int r = 0; r < 4; ++r)
          dst[((size_t)(b * H_NUM + h) * SEQ + (sl0 + r)) * HD + hd] =
              f2bf(acc[m][n][r] + bs);
      }
    }
  }
}

// ---------------- flash attention ----------------
// qb,kb: [b][h][s][hd] bf16 ; vt: [b][h][hd][s] bf16 ; out fp32 [b][s][h*64+hd]
__global__ __launch_bounds__(256) void attn_fwd(
    const unsigned short* __restrict__ qb, const unsigned short* __restrict__ kb,
    const unsigned short* __restrict__ vt, const float* __restrict__ Bb,
    float* __restrict__ out) {
  __shared__ __align__(16) unsigned short Kl[64 * 80];      // [key][hd + pad]
  __shared__ __align__(16) unsigned short Vl[64 * 80];      // [hd][key + pad]
  __shared__ __align__(16) unsigned short Pl[4][16 * 80];   // per-wave [q][key + pad]

  const int bh = blockIdx.y;
  const int b = bh >> 4, h = bh & 15;
  const int q0 = blockIdx.x * 64;
  const int t = threadIdx.x, w = t >> 6, l = t & 63;
  const int lg = l >> 4, lc = l & 15;

  const unsigned short* Q = qb + (size_t)bh * SEQ * HD;
  const unsigned short* K = kb + (size_t)bh * SEQ * HD;
  const unsigned short* V = vt + (size_t)bh * HD * SEQ;
  const float Bh = Bb[h];

  // Q fragments for this wave's 16 rows
  const int qrow = q0 + w * 16 + lc;
  s8v qf[2];
  qf[0] = *(const s8v*)(Q + (size_t)qrow * HD + 8 * lg);
  qf[1] = *(const s8v*)(Q + (size_t)qrow * HD + 32 + 8 * lg);

  f4v acc[4];
#pragma unroll
  for (int n = 0; n < 4; ++n) acc[n] = (f4v){0.f, 0.f, 0.f, 0.f};
  float mrow[4], lrow[4];
#pragma unroll
  for (int r = 0; r < 4; ++r) { mrow[r] = -1e30f; lrow[r] = 0.f; }

  const int sr = t >> 2;         // staging row (key for Kl, hd for Vl)
  const int scc = (t & 3) * 8;   // staging col chunk

  for (int kt = 0; kt < SEQ / 64; ++kt) {
    const int key0 = kt * 64;
    __syncthreads();
#pragma unroll
    for (int i = 0; i < 2; ++i) {
      *(s8v*)(Kl + sr * 80 + scc + i * 32) =
          *(const s8v*)(K + (size_t)(key0 + sr) * HD + scc + i * 32);
      *(s8v*)(Vl + sr * 80 + scc + i * 32) =
          *(const s8v*)(V + (size_t)sr * SEQ + key0 + scc + i * 32);
    }
    __syncthreads();

    // QK^T: 4 tiles of 16 keys
    f4v s[4];
#pragma unroll
    for (int ktile = 0; ktile < 4; ++ktile) {
      f4v c = (f4v){0.f, 0.f, 0.f, 0.f};
      s8v kf0 = *(const s8v*)(Kl + (ktile * 16 + lc) * 80 + 8 * lg);
      s8v kf1 = *(const s8v*)(Kl + (ktile * 16 + lc) * 80 + 32 + 8 * lg);
      c = mfma16(qf[0], kf0, c);
      c = mfma16(qf[1], kf1, c);
#pragma unroll
      for (int r = 0; r < 4; ++r) s[ktile][r] = c[r] * 0.125f + Bh;
    }

    // online softmax (rows live across the 16-lane group)
    float tm[4];
#pragma unroll
    for (int r = 0; r < 4; ++r) {
      tm[r] = fmaxf(fmaxf(s[0][r], s[1][r]), fmaxf(s[2][r], s[3][r]));
      tm[r] = fmaxf(tm[r], __shfl_xor(tm[r], 1));
      tm[r] = fmaxf(tm[r], __shfl_xor(tm[r], 2));
      tm[r] = fmaxf(tm[r], __shfl_xor(tm[r], 4));
      tm[r] = fmaxf(tm[r], __shfl_xor(tm[r], 8));
    }
    float f[4], ps[4];
#pragma unroll
    for (int r = 0; r < 4; ++r) {
      float mn = fmaxf(mrow[r], tm[r]);
      f[r] = __expf(mrow[r] - mn);
      mrow[r] = mn;
      ps[r] = 0.f;
    }
#pragma unroll
    for (int ktile = 0; ktile < 4; ++ktile)
#pragma unroll
      for (int r = 0; r < 4; ++r) {
        float p = __expf(s[ktile][r] - mrow[r]);
        ps[r] += p;
        Pl[w][(4 * lg + r) * 80 + ktile * 16 + lc] = f2bf(p);
      }
#pragma unroll
    for (int r = 0; r < 4; ++r) {
      ps[r] += __shfl_xor(ps[r], 1);
      ps[r] += __shfl_xor(ps[r], 2);
      ps[r] += __shfl_xor(ps[r], 4);
      ps[r] += __shfl_xor(ps[r], 8);
      lrow[r] = lrow[r] * f[r] + ps[r];
    }
#pragma unroll
    for (int n = 0; n < 4; ++n)
#pragma unroll
      for (int r = 0; r < 4; ++r) acc[n][r] *= f[r];

    // PV
#pragma unroll
    for (int kc = 0; kc < 2; ++kc) {
      s8v pa = *(const s8v*)(Pl[w] + lc * 80 + kc * 32 + 8 * lg);
#pragma unroll
      for (int n = 0; n < 4; ++n) {
        s8v vf = *(const s8v*)(Vl + (n * 16 + lc) * 80 + kc * 32 + 8 * lg);
        acc[n] = mfma16(pa, vf, acc[n]);
      }
    }
  }

  // epilogue
#pragma unroll
  for (int n = 0; n < 4; ++n)
#pragma unroll
    for (int r = 0; r < 4; ++r) {
      const int qg = q0 + w * 16 + 4 * lg + r;
      out[((size_t)(b * SEQ + qg)) * D_DIM + h * 64 + n * 16 + lc] =
          acc[n][r] / lrow[r];
    }
}

extern "C" void kernel_launch(void* const* d_in, const int* in_sizes, int n_in,
                              void* d_out, int out_size, void* d_ws, size_t ws_size,
                              hipStream_t stream) {
  const float* x = (const float*)d_in[0];
  const float* Wq = (const float*)d_in[1];
  const float* bq = (const float*)d_in[2];
  const float* Wk = (const float*)d_in[3];
  const float* bk = (const float*)d_in[4];
  const float* Wv = (const float*)d_in[5];
  const float* bv = (const float*)d_in[6];
  const float* Bb = (const float*)d_in[7];
  float* out = (float*)d_out;

  char* ws = (char*)d_ws;
  unsigned short* Xb = (unsigned short*)ws;                          // 8 MiB
  unsigned short* Wb = (unsigned short*)(ws + (8ull << 20));         // 6 MiB
  unsigned short* qb = (unsigned short*)(ws + (14ull << 20));        // 8 MiB
  unsigned short* kb = (unsigned short*)(ws + (22ull << 20));        // 8 MiB
  unsigned short* vt = (unsigned short*)(ws + (30ull << 20));        // 8 MiB

  // converts
  cvt_bf16<<<1024, 256, 0, stream>>>(x, Xb, (MROWS * D_DIM) / 4);
  cvt_bf16<<<512, 256, 0, stream>>>(Wq, Wb + 0 * D_DIM * D_DIM, (D_DIM * D_DIM) / 4);
  cvt_bf16<<<512, 256, 0, stream>>>(Wk, Wb + 1 * D_DIM * D_DIM, (D_DIM * D_DIM) / 4);
  cvt_bf16<<<512, 256, 0, stream>>>(Wv, Wb + 2 * D_DIM * D_DIM, (D_DIM * D_DIM) / 4);

  // QKV projection
  dim3 ggrid(MROWS / 128, D_DIM / 128, 3);
  qkv_gemm<<<ggrid, 256, 0, stream>>>(Xb, Wb, bq, bk, bv, qb, kb, vt);

  // attention
  dim3 agrid(SEQ / 64, BSZ * H_NUM);
  attn_fwd<<<agrid, 256, 0, stream>>>(qb, kb, vt, Bb, out);
}

// Round 3
// 144.673 us; speedup vs baseline: 1.2488x; 1.2488x over previous
//
#include <hip/hip_runtime.h>
#include <stdint.h>

typedef __attribute__((ext_vector_type(8))) short s8v;
typedef __attribute__((ext_vector_type(4))) short s4v;
typedef __attribute__((ext_vector_type(4))) float f4v;

#define D_DIM 1024
#define H_NUM 16
#define HD 64
#define SEQ 2048
#define BSZ 2
#define MROWS (BSZ * SEQ)   // 4096
#define LOG2E 1.4426950408889634f

__device__ __forceinline__ unsigned short f2bf(float f) {
  unsigned u = __builtin_bit_cast(unsigned, f);
  u += 0x7fffu + ((u >> 16) & 1u);
  return (unsigned short)(u >> 16);
}

__device__ __forceinline__ unsigned int pack2bf(float a, float b) {
  return (unsigned int)f2bf(a) | ((unsigned int)f2bf(b) << 16);
}

__device__ __forceinline__ void async16(const unsigned short* g, unsigned short* l) {
  __builtin_amdgcn_global_load_lds(
      (__attribute__((address_space(1))) unsigned int*)(uintptr_t)g,
      (__attribute__((address_space(3))) unsigned int*)l, 16, 0, 0);
}

__device__ __forceinline__ f4v mfma16(s8v a, s8v b, f4v c) {
  return __builtin_amdgcn_mfma_f32_16x16x32_bf16(a, b, c, 0, 0, 0);
}

__device__ __forceinline__ void barrier_raw() {
  __builtin_amdgcn_sched_barrier(0);
  __builtin_amdgcn_s_barrier();
  __builtin_amdgcn_sched_barrier(0);
}
#define WAITVM0() asm volatile("s_waitcnt vmcnt(0)" ::: "memory")

// ---------------- fused fp32 -> bf16 convert (x, Wq, Wk, Wv) ----------------
__global__ __launch_bounds__(256) void cvt_all(
    const float* __restrict__ x, const float* __restrict__ Wq,
    const float* __restrict__ Wk, const float* __restrict__ Wv,
    unsigned short* __restrict__ Xb, unsigned short* __restrict__ Wb) {
  const int NX = MROWS * D_DIM / 4;   // 1048576 f4 chunks
  const int NW = D_DIM * D_DIM / 4;   // 262144 per W
  int i = blockIdx.x * 256 + threadIdx.x;
  const float* src;
  unsigned short* dst;
  int off;
  if (i < NX) {
    src = x; dst = Xb; off = i;
  } else if (i < NX + NW) {
    src = Wq; dst = Wb; off = i - NX;
  } else if (i < NX + 2 * NW) {
    src = Wk; dst = Wb + D_DIM * D_DIM; off = i - NX - NW;
  } else {
    src = Wv; dst = Wb + 2 * D_DIM * D_DIM; off = i - NX - 2 * NW;
  }
  f4v v = *(const f4v*)(src + (size_t)off * 4);
  s4v o;
  o[0] = (short)f2bf(v[0]);
  o[1] = (short)f2bf(v[1]);
  o[2] = (short)f2bf(v[2]);
  o[3] = (short)f2bf(v[3]);
  *(s4v*)(dst + (size_t)off * 4) = o;
}

// ---------------- QKV projection GEMM (unchanged structure) ----------------
__global__ __launch_bounds__(256) void qkv_gemm(
    const unsigned short* __restrict__ Xb, const unsigned short* __restrict__ Wb,
    const float* __restrict__ bq, const float* __restrict__ bk,
    const float* __restrict__ bv, unsigned short* __restrict__ qb,
    unsigned short* __restrict__ kb, unsigned short* __restrict__ vt) {
  __shared__ __align__(16) unsigned short At[128 * 64];
  __shared__ __align__(16) unsigned short Bt[128 * 64];

  const int z = blockIdx.z;
  const unsigned short* W = Wb + z * (D_DIM * D_DIM);
  const float* bias = (z == 0) ? bq : ((z == 1) ? bk : bv);
  const int row0 = blockIdx.x * 128;
  const int col0 = blockIdx.y * 128;
  const int t = threadIdx.x;
  const int w = t >> 6, l = t & 63;
  const int wr = w >> 1, wc = w & 1;
  const int lg = l >> 4, lc = l & 15;

  f4v acc[4][4];
#pragma unroll
  for (int m = 0; m < 4; ++m)
#pragma unroll
    for (int n = 0; n < 4; ++n) acc[m][n] = (f4v){0.f, 0.f, 0.f, 0.f};

  const int sr = t >> 3;
  const int sc = (t & 7) * 8;
  const int arow = wr * 64 + lc;
  const int brow = wc * 64 + lc;
  const int koff = 8 * lg;

  for (int it = 0; it < 16; ++it) {
    const int k0 = it * 64;
    __syncthreads();
#pragma unroll
    for (int i = 0; i < 4; ++i) {
      async16(Xb + (size_t)(row0 + i * 32 + sr) * D_DIM + k0 + sc, At + i * 2048 + t * 8);
      async16(W + (size_t)(col0 + i * 32 + sr) * D_DIM + k0 + sc, Bt + i * 2048 + t * 8);
    }
    __syncthreads();
#pragma unroll
    for (int kc = 0; kc < 2; ++kc) {
      s8v a[4], b[4];
#pragma unroll
      for (int m = 0; m < 4; ++m)
        a[m] = *(const s8v*)(At + (arow + m * 16) * 64 + kc * 32 + koff);
#pragma unroll
      for (int n = 0; n < 4; ++n)
        b[n] = *(const s8v*)(Bt + (brow + n * 16) * 64 + kc * 32 + koff);
#pragma unroll
      for (int m = 0; m < 4; ++m)
#pragma unroll
        for (int n = 0; n < 4; ++n) acc[m][n] = mfma16(a[m], b[n], acc[m][n]);
    }
  }

#pragma unroll
  for (int m = 0; m < 4; ++m) {
    const int sg0 = row0 + wr * 64 + m * 16 + 4 * lg;
    const int b = sg0 >> 11;
    const int sl0 = sg0 & (SEQ - 1);
#pragma unroll
    for (int n = 0; n < 4; ++n) {
      const int j = col0 + wc * 64 + n * 16 + lc;
      const int h = j >> 6, hd = j & 63;
      const float bs = bias[j];
      if (z == 2) {
        s4v o;
#pragma unroll
        for (int r = 0; r < 4; ++r) o[r] = (short)f2bf(acc[m][n][r] + bs);
        *(s4v*)(vt + ((size_t)(b * H_NUM + h) * HD + hd) * SEQ + sl0) = o;
      } else {
        unsigned short* dst = (z == 0) ? qb : kb;
#pragma unroll
        for (int r = 0; r < 4; ++r)
          dst[((size_t)(b * H_NUM + h) * SEQ + (sl0 + r)) * HD + hd] =
              f2bf(acc[m][n][r] + bs);
      }
    }
  }
}

// ---------------- flash attention: swapped QK^T, dbuf async staging ----------------
// qb,kb: [b][h][s][hd] bf16 ; vt: [b][h][hd][s] bf16 ; out fp32 [b][s][D]
// LDS tiles: 64 rows x 64 shorts (128B rows), chunk XOR-swizzle: chunk ^= (row&7)
__device__ __forceinline__ void stage_kv(const unsigned short* __restrict__ K,
                                         const unsigned short* __restrict__ V,
                                         unsigned short* Kd, unsigned short* Vd,
                                         int kt, int w, int l) {
  const int rr = l >> 3;                 // 0..7 (row within 8-row group)
  const int schunk = (l & 7) ^ rr;       // pre-swizzled source chunk
  const int key0 = kt * 64;
#pragma unroll
  for (int i = 0; i < 2; ++i) {
    const int row = w * 16 + i * 8 + rr;
    async16(K + (size_t)(key0 + row) * HD + schunk * 8, Kd + (w * 16 + i * 8) * 64);
    async16(V + (size_t)row * SEQ + key0 + schunk * 8, Vd + (w * 16 + i * 8) * 64);
  }
}

__global__ __launch_bounds__(256, 4) void attn_fwd(
    const unsigned short* __restrict__ qb, const unsigned short* __restrict__ kb,
    const unsigned short* __restrict__ vt, const float* __restrict__ Bb,
    float* __restrict__ out) {
  __shared__ __align__(16) unsigned short Kl[2][64 * 64];
  __shared__ __align__(16) unsigned short Vl[2][64 * 64];
  __shared__ __align__(16) unsigned short Pl[4][16 * 64];

  const int bh = blockIdx.x;              // bh on x: bid%8 == bh%8 -> same-bh blocks share an XCD L2
  const int b = bh >> 4, h = bh & 15;
  const int q0 = blockIdx.y * 64;
  const int t = threadIdx.x, w = t >> 6, l = t & 63;
  const int lg = l >> 4, lc = l & 15;
  const int swz = lc & 7;

  const unsigned short* Q = qb + (size_t)bh * SEQ * HD;
  const unsigned short* K = kb + (size_t)bh * SEQ * HD;
  const unsigned short* V = vt + (size_t)bh * HD * SEQ;
  const float SC = 0.125f * LOG2E;
  const float Bh = Bb[h] * LOG2E;

  // Q fragments (B-operand: col=q=lc, k=d)
  const int qrow = q0 + w * 16 + lc;
  s8v qf0 = *(const s8v*)(Q + (size_t)qrow * HD + 8 * lg);
  s8v qf1 = *(const s8v*)(Q + (size_t)qrow * HD + 32 + 8 * lg);

  f4v acc[4];
#pragma unroll
  for (int n = 0; n < 4; ++n) acc[n] = (f4v){0.f, 0.f, 0.f, 0.f};
  float m = -3.0e38f, lsum = 0.f;

  // prologue: stage tile 0
  stage_kv(K, V, Kl[0], Vl[0], 0, w, l);
  WAITVM0();
  barrier_raw();

  int cur = 0;
  for (int kt = 0; kt < SEQ / 64; ++kt) {
    if (kt < SEQ / 64 - 1)
      stage_kv(K, V, Kl[cur ^ 1], Vl[cur ^ 1], kt + 1, w, l);

    const unsigned short* Kb_ = Kl[cur];
    const unsigned short* Vb_ = Vl[cur];

    // QK^T swapped: S^T = K * Q^T  -> lane holds S[key=kt4*16+4lg+r][q=lc]
    f4v sv[4];
    __builtin_amdgcn_s_setprio(1);
#pragma unroll
    for (int kt4 = 0; kt4 < 4; ++kt4) {
      const int row = kt4 * 16 + lc;
      s8v kf0 = *(const s8v*)(Kb_ + row * 64 + ((lg ^ swz) * 8));
      s8v kf1 = *(const s8v*)(Kb_ + row * 64 + (((4 + lg) ^ swz) * 8));
      f4v c = (f4v){0.f, 0.f, 0.f, 0.f};
      c = mfma16(kf0, qf0, c);
      c = mfma16(kf1, qf1, c);
      sv[kt4] = c;
    }
    __builtin_amdgcn_s_setprio(0);

#pragma unroll
    for (int kt4 = 0; kt4 < 4; ++kt4)
#pragma unroll
      for (int r = 0; r < 4; ++r) sv[kt4][r] = sv[kt4][r] * SC + Bh;

    // row max (row = q = lc, lane-local 16 values + reduce over 4 lg lanes)
    float t0 = fmaxf(fmaxf(sv[0][0], sv[0][1]), fmaxf(sv[0][2], sv[0][3]));
    float t1 = fmaxf(fmaxf(sv[1][0], sv[1][1]), fmaxf(sv[1][2], sv[1][3]));
    float t2 = fmaxf(fmaxf(sv[2][0], sv[2][1]), fmaxf(sv[2][2], sv[2][3]));
    float t3 = fmaxf(fmaxf(sv[3][0], sv[3][1]), fmaxf(sv[3][2], sv[3][3]));
    float tmax = fmaxf(fmaxf(t0, t1), fmaxf(t2, t3));
    tmax = fmaxf(tmax, __shfl_xor(tmax, 16));
    tmax = fmaxf(tmax, __shfl_xor(tmax, 32));

    const float mn = fmaxf(m, tmax);
    const float fs = exp2f(m - mn);
    m = mn;

    // p = exp2(s - m), overwrite sv
#pragma unroll
    for (int kt4 = 0; kt4 < 4; ++kt4)
#pragma unroll
      for (int r = 0; r < 4; ++r) sv[kt4][r] = exp2f(sv[kt4][r] - mn);

    float s0 = (sv[0][0] + sv[0][1]) + (sv[0][2] + sv[0][3]);
    float s1 = (sv[1][0] + sv[1][1]) + (sv[1][2] + sv[1][3]);
    float s2 = (sv[2][0] + sv[2][1]) + (sv[2][2] + sv[2][3]);
    float s3 = (sv[3][0] + sv[3][1]) + (sv[3][2] + sv[3][3]);
    float ps = (s0 + s1) + (s2 + s3);
    ps += __shfl_xor(ps, 16);
    ps += __shfl_xor(ps, 32);
    lsum = lsum * fs + ps;

#pragma unroll
    for (int n = 0; n < 4; ++n)
#pragma unroll
      for (int r = 0; r < 4; ++r) acc[n][r] *= fs;

    // pack P to bf16 pairs, write b64 to per-wave Pl (swizzled)
#pragma unroll
    for (int kt4 = 0; kt4 < 4; ++kt4) {
      uint2 dw;
      dw.x = pack2bf(sv[kt4][0], sv[kt4][1]);
      dw.y = pack2bf(sv[kt4][2], sv[kt4][3]);
      const int chunk = (2 * kt4 + (lg >> 1)) ^ swz;
      *(uint2*)(Pl[w] + lc * 64 + chunk * 8 + 4 * (lg & 1)) = dw;
    }

    // PV: O^T = V^T * P^T  (A = V^T rows=d, B = P^T cols=q)
    __builtin_amdgcn_s_setprio(1);
#pragma unroll
    for (int kc = 0; kc < 2; ++kc) {
      s8v pb = *(const s8v*)(Pl[w] + lc * 64 + (((kc * 4 + lg) ^ swz) * 8));
#pragma unroll
      for (int n = 0; n < 4; ++n) {
        s8v vf = *(const s8v*)(Vb_ + (n * 16 + lc) * 64 + (((kc * 4 + lg) ^ swz) * 8));
        acc[n] = mfma16(vf, pb, acc[n]);
      }
    }
    __builtin_amdgcn_s_setprio(0);

    WAITVM0();
    barrier_raw();
    cur ^= 1;
  }

  // epilogue: lane holds O[d = n*16+4lg+r][q = q0+w*16+lc]
  const float inv = 1.0f / lsum;
  const int q = q0 + w * 16 + lc;
#pragma unroll
  for (int n = 0; n < 4; ++n) {
    f4v o;
#pragma unroll
    for (int r = 0; r < 4; ++r) o[r] = acc[n][r] * inv;
    *(f4v*)(out + ((size_t)(b * SEQ + q)) * D_DIM + h * 64 + n * 16 + 4 * lg) = o;
  }
}

extern "C" void kernel_launch(void* const* d_in, const int* in_sizes, int n_in,
                              void* d_out, int out_size, void* d_ws, size_t ws_size,
                              hipStream_t stream) {
  const float* x = (const float*)d_in[0];
  const float* Wq = (const float*)d_in[1];
  const float* bq = (const float*)d_in[2];
  const float* Wk = (const float*)d_in[3];
  const float* bk = (const float*)d_in[4];
  const float* Wv = (const float*)d_in[5];
  const float* bv = (const float*)d_in[6];
  const float* Bb = (const float*)d_in[7];
  float* out = (float*)d_out;

  char* ws = (char*)d_ws;
  unsigned short* Xb = (unsigned short*)ws;                          // 8 MiB
  unsigned short* Wb = (unsigned short*)(ws + (8ull << 20));         // 6 MiB
  unsigned short* qb = (unsigned short*)(ws + (14ull << 20));        // 8 MiB
  unsigned short* kb = (unsigned short*)(ws + (22ull << 20));        // 8 MiB
  unsigned short* vt = (unsigned short*)(ws + (30ull << 20));        // 8 MiB

  // fused converts: (NX + 3*NW) / 256 = 7168 blocks, exact cover
  cvt_all<<<7168, 256, 0, stream>>>(x, Wq, Wk, Wv, Xb, Wb);

  dim3 ggrid(MROWS / 128, D_DIM / 128, 3);
  qkv_gemm<<<ggrid, 256, 0, stream>>>(Xb, Wb, bq, bk, bv, qb, kb, vt);

  dim3 agrid(BSZ * H_NUM, SEQ / 64);   // bh on x for XCD/L2 affinity
  attn_fwd<<<agrid, 256, 0, stream>>>(qb, kb, vt, Bb, out);
}

// Round 4
// 103.379 us; speedup vs baseline: 1.7477x; 1.3994x over previous
//
#include <hip/hip_runtime.h>
#include <stdint.h>

typedef __attribute__((ext_vector_type(8))) short s8v;
typedef __attribute__((ext_vector_type(4))) short s4v;
typedef __attribute__((ext_vector_type(4))) float f4v;

#define D_DIM 1024
#define H_NUM 16
#define HD 64
#define SEQ 2048
#define BSZ 2
#define MROWS (BSZ * SEQ)   // 4096
#define LOG2E 1.4426950408889634f

__device__ __forceinline__ unsigned short f2bf(float f) {
  unsigned u = __builtin_bit_cast(unsigned, f);
  u += 0x7fffu + ((u >> 16) & 1u);
  return (unsigned short)(u >> 16);
}

// single-instruction 2^x (bypasses libm denormal fixups)
__device__ __forceinline__ float exp2q(float x) {
  float r;
  asm("v_exp_f32 %0, %1" : "=v"(r) : "v"(x));
  return r;
}

// pack 2 fp32 -> bf16x2 in one instruction (RNE)
__device__ __forceinline__ unsigned int cvtpk(float a, float b) {
  unsigned int r;
  asm("v_cvt_pk_bf16_f32 %0, %1, %2" : "=v"(r) : "v"(a), "v"(b));
  return r;
}

__device__ __forceinline__ void async16(const unsigned short* g, unsigned short* l) {
  __builtin_amdgcn_global_load_lds(
      (__attribute__((address_space(1))) unsigned int*)(uintptr_t)g,
      (__attribute__((address_space(3))) unsigned int*)l, 16, 0, 0);
}

__device__ __forceinline__ f4v mfma16(s8v a, s8v b, f4v c) {
  return __builtin_amdgcn_mfma_f32_16x16x32_bf16(a, b, c, 0, 0, 0);
}

__device__ __forceinline__ void barrier_raw() {
  __builtin_amdgcn_sched_barrier(0);
  __builtin_amdgcn_s_barrier();
  __builtin_amdgcn_sched_barrier(0);
}
#define WAITVM0() asm volatile("s_waitcnt vmcnt(0)" ::: "memory")

// ---------------- fused fp32 -> bf16 convert (x, Wq, Wk, Wv) ----------------
__global__ __launch_bounds__(256) void cvt_all(
    const float* __restrict__ x, const float* __restrict__ Wq,
    const float* __restrict__ Wk, const float* __restrict__ Wv,
    unsigned short* __restrict__ Xb, unsigned short* __restrict__ Wb) {
  const int NX = MROWS * D_DIM / 4;
  const int NW = D_DIM * D_DIM / 4;
  int i = blockIdx.x * 256 + threadIdx.x;
  const float* src;
  unsigned short* dst;
  int off;
  if (i < NX) {
    src = x; dst = Xb; off = i;
  } else if (i < NX + NW) {
    src = Wq; dst = Wb; off = i - NX;
  } else if (i < NX + 2 * NW) {
    src = Wk; dst = Wb + D_DIM * D_DIM; off = i - NX - NW;
  } else {
    src = Wv; dst = Wb + 2 * D_DIM * D_DIM; off = i - NX - 2 * NW;
  }
  f4v v = *(const f4v*)(src + (size_t)off * 4);
  s4v o;
  o[0] = (short)f2bf(v[0]);
  o[1] = (short)f2bf(v[1]);
  o[2] = (short)f2bf(v[2]);
  o[3] = (short)f2bf(v[3]);
  *(s4v*)(dst + (size_t)off * 4) = o;
}

// ---------------- QKV projection GEMM: KSTEP=32, dbuf 2-phase, swizzled ----------------
// Y[4096][1024] = Xb * W^T + bias. z=0 -> qb (pre-scaled by 0.125*log2e),
// z=1 -> kb, z=2 -> vt transposed [b][h][hd][s].
// LDS [128][32] per buffer; chunk swizzle: lds_chunk = logical_chunk ^ ((row>>1)&3)
__global__ __launch_bounds__(256) void qkv_gemm(
    const unsigned short* __restrict__ Xb, const unsigned short* __restrict__ Wb,
    const float* __restrict__ bq, const float* __restrict__ bk,
    const float* __restrict__ bv, unsigned short* __restrict__ qb,
    unsigned short* __restrict__ kb, unsigned short* __restrict__ vt) {
  __shared__ __align__(16) unsigned short At[2][128 * 32];
  __shared__ __align__(16) unsigned short Bt[2][128 * 32];

  const int z = blockIdx.z;
  const unsigned short* W = Wb + z * (D_DIM * D_DIM);
  const float* bias = (z == 0) ? bq : ((z == 1) ? bk : bv);
  const int row0 = blockIdx.x * 128;
  const int col0 = blockIdx.y * 128;
  const int t = threadIdx.x;
  const int w = t >> 6, l = t & 63;
  const int wr = w >> 1, wc = w & 1;
  const int lg = l >> 4, lc = l & 15;

  f4v acc[4][4];
#pragma unroll
  for (int m = 0; m < 4; ++m)
#pragma unroll
    for (int n = 0; n < 4; ++n) acc[m][n] = (f4v){0.f, 0.f, 0.f, 0.f};

  // staging: thread t loads row=t>>2 (0..63, +64 second round), source chunk pre-swizzled
  const int srow = t >> 2;
  const int sch = (t & 3) ^ ((t >> 3) & 3);   // = (t&3) ^ ((srow>>1)&3)
  const unsigned short* Asrc = Xb + (size_t)(row0 + srow) * D_DIM + sch * 8;
  const unsigned short* Bsrc = W + (size_t)(col0 + srow) * D_DIM + sch * 8;

  // fragment reads: lds chunk for logical k-chunk lg of row (..+lc)
  const int rch = lg ^ ((lc >> 1) & 3);
  const int arow = wr * 64 + lc;
  const int brow = wc * 64 + lc;

#define STAGE(b, k0)                                                        \
  do {                                                                      \
    async16(Asrc + (k0), At[b] + t * 8);                                    \
    async16(Asrc + (k0) + 64 * D_DIM, At[b] + 2048 + t * 8);                \
    async16(Bsrc + (k0), Bt[b] + t * 8);                                    \
    async16(Bsrc + (k0) + 64 * D_DIM, Bt[b] + 2048 + t * 8);                \
  } while (0)

  STAGE(0, 0);
  WAITVM0();
  barrier_raw();

  int cur = 0;
  for (int it = 0; it < 32; ++it) {
    if (it < 31) STAGE(cur ^ 1, (it + 1) * 32);
    s8v a[4], b[4];
#pragma unroll
    for (int m = 0; m < 4; ++m)
      a[m] = *(const s8v*)(At[cur] + (arow + m * 16) * 32 + rch * 8);
#pragma unroll
    for (int n = 0; n < 4; ++n)
      b[n] = *(const s8v*)(Bt[cur] + (brow + n * 16) * 32 + rch * 8);
    __builtin_amdgcn_s_setprio(1);
#pragma unroll
    for (int m = 0; m < 4; ++m)
#pragma unroll
      for (int n = 0; n < 4; ++n) acc[m][n] = mfma16(a[m], b[n], acc[m][n]);
    __builtin_amdgcn_s_setprio(0);
    WAITVM0();
    barrier_raw();
    cur ^= 1;
  }
#undef STAGE

  const float SCQ = 0.125f * LOG2E;   // folded into Q so attn needs no per-score scale
#pragma unroll
  for (int m = 0; m < 4; ++m) {
    const int sg0 = row0 + wr * 64 + m * 16 + 4 * lg;
    const int b = sg0 >> 11;
    const int sl0 = sg0 & (SEQ - 1);
#pragma unroll
    for (int n = 0; n < 4; ++n) {
      const int j = col0 + wc * 64 + n * 16 + lc;
      const int h = j >> 6, hd = j & 63;
      const float bs = bias[j];
      if (z == 2) {
        s4v o;
#pragma unroll
        for (int r = 0; r < 4; ++r) o[r] = (short)f2bf(acc[m][n][r] + bs);
        *(s4v*)(vt + ((size_t)(b * H_NUM + h) * HD + hd) * SEQ + sl0) = o;
      } else if (z == 0) {
#pragma unroll
        for (int r = 0; r < 4; ++r)
          qb[((size_t)(b * H_NUM + h) * SEQ + (sl0 + r)) * HD + hd] =
              f2bf((acc[m][n][r] + bs) * SCQ);
      } else {
#pragma unroll
        for (int r = 0; r < 4; ++r)
          kb[((size_t)(b * H_NUM + h) * SEQ + (sl0 + r)) * HD + hd] =
              f2bf(acc[m][n][r] + bs);
      }
    }
  }
}

// ---------------- flash attention ----------------
// Q pre-scaled (0.125*log2e). B dropped: constant over key axis -> softmax-invariant.
// Defer-max (THR=8): m starts -3e38 (first tile always triggers, exp2(-huge)=0);
// common path has NO cross-lane ops. lsum is a lane-local partial, reduced once.
__global__ __launch_bounds__(256, 4) void attn_fwd(
    const unsigned short* __restrict__ qb, const unsigned short* __restrict__ kb,
    const unsigned short* __restrict__ vt, const float* __restrict__ Bb,
    float* __restrict__ out) {
  __shared__ __align__(16) unsigned short Kl[2][64 * 64];
  __shared__ __align__(16) unsigned short Vl[2][64 * 64];
  __shared__ __align__(16) unsigned short Pl[4][16 * 64];

  const int bh = blockIdx.x;
  const int b = bh >> 4, h = bh & 15;
  const int q0 = blockIdx.y * 64;
  const int t = threadIdx.x, w = t >> 6, l = t & 63;
  const int lg = l >> 4, lc = l & 15;
  const int swz = lc & 7;
  (void)Bb;

  const unsigned short* Q = qb + (size_t)bh * SEQ * HD;
  const unsigned short* K = kb + (size_t)bh * SEQ * HD;
  const unsigned short* V = vt + (size_t)bh * HD * SEQ;

  const int qrow = q0 + w * 16 + lc;
  s8v qf0 = *(const s8v*)(Q + (size_t)qrow * HD + 8 * lg);
  s8v qf1 = *(const s8v*)(Q + (size_t)qrow * HD + 32 + 8 * lg);

  f4v acc[4];
#pragma unroll
  for (int n = 0; n < 4; ++n) acc[n] = (f4v){0.f, 0.f, 0.f, 0.f};
  float m = -3.0e38f, thr = -3.0e38f, lsum = 0.f;

  // staging pointers (incremented per tile)
  const int rr = l >> 3;
  const int sch = (l & 7) ^ rr;
  const unsigned short* Kst = K + (size_t)(w * 16 + rr) * HD + sch * 8;
  const unsigned short* Vst = V + (size_t)(w * 16 + rr) * SEQ + sch * 8;
  unsigned short* Kd0 = Kl[0] + (w * 16) * 64;
  unsigned short* Vd0 = Vl[0] + (w * 16) * 64;
  const int ldsw = 64 * 64;   // buffer stride (shorts)

#define STAGE_KV(bsel)                                                      \
  do {                                                                      \
    async16(Kst, Kd0 + (bsel) * ldsw);                                      \
    async16(Kst + 8 * HD, Kd0 + (bsel) * ldsw + 8 * 64);                    \
    async16(Vst, Vd0 + (bsel) * ldsw);                                      \
    async16(Vst + 8 * SEQ, Vd0 + (bsel) * ldsw + 8 * 64);                   \
    Kst += 64 * HD;                                                         \
    Vst += 64;                                                              \
  } while (0)

  STAGE_KV(0);
  WAITVM0();
  barrier_raw();

  int cur = 0;
  for (int kt = 0; kt < SEQ / 64; ++kt) {
    if (kt < SEQ / 64 - 1) STAGE_KV(cur ^ 1);

    const unsigned short* Kb_ = Kl[cur];
    const unsigned short* Vb_ = Vl[cur];

    // QK^T swapped: lane holds S^T[key=16*kt4+4lg+r][q=lc] (already in exp2 domain)
    f4v sv[4];
    __builtin_amdgcn_s_setprio(1);
#pragma unroll
    for (int kt4 = 0; kt4 < 4; ++kt4) {
      const int row = kt4 * 16 + lc;
      s8v kf0 = *(const s8v*)(Kb_ + row * 64 + ((lg ^ swz) * 8));
      s8v kf1 = *(const s8v*)(Kb_ + row * 64 + (((4 + lg) ^ swz) * 8));
      f4v c = (f4v){0.f, 0.f, 0.f, 0.f};
      c = mfma16(kf0, qf0, c);
      c = mfma16(kf1, qf1, c);
      sv[kt4] = c;
    }
    __builtin_amdgcn_s_setprio(0);

    // lane-local max of 16 (compiler fuses to max3)
    float t0 = fmaxf(fmaxf(sv[0][0], sv[0][1]), fmaxf(sv[0][2], sv[0][3]));
    float t1 = fmaxf(fmaxf(sv[1][0], sv[1][1]), fmaxf(sv[1][2], sv[1][3]));
    float t2 = fmaxf(fmaxf(sv[2][0], sv[2][1]), fmaxf(sv[2][2], sv[2][3]));
    float t3 = fmaxf(fmaxf(sv[3][0], sv[3][1]), fmaxf(sv[3][2], sv[3][3]));
    float tmax = fmaxf(fmaxf(t0, t1), fmaxf(t2, t3));

    if (!__all(tmax <= thr)) {   // rare: full reduce + rescale
      float tr = tmax;
      tr = fmaxf(tr, __shfl_xor(tr, 16));
      tr = fmaxf(tr, __shfl_xor(tr, 32));
      const float mn = fmaxf(m, tr);
      const float fs = exp2q(m - mn);
      m = mn;
      thr = mn + 8.0f;
#pragma unroll
      for (int n = 0; n < 4; ++n)
#pragma unroll
        for (int r = 0; r < 4; ++r) acc[n][r] *= fs;
      lsum *= fs;
    }

    // p = exp2(s - m); accumulate lane-local sum; pack to bf16
    float psum = 0.f;
#pragma unroll
    for (int kt4 = 0; kt4 < 4; ++kt4) {
#pragma unroll
      for (int r = 0; r < 4; ++r) sv[kt4][r] = exp2q(sv[kt4][r] - m);
      psum += (sv[kt4][0] + sv[kt4][1]) + (sv[kt4][2] + sv[kt4][3]);
    }
    lsum += psum;

#pragma unroll
    for (int kt4 = 0; kt4 < 4; ++kt4) {
      uint2 dw;
      dw.x = cvtpk(sv[kt4][0], sv[kt4][1]);
      dw.y = cvtpk(sv[kt4][2], sv[kt4][3]);
      const int chunk = (2 * kt4 + (lg >> 1)) ^ swz;
      *(uint2*)(Pl[w] + lc * 64 + chunk * 8 + 4 * (lg & 1)) = dw;
    }

    // PV: O^T = V^T * P^T
    __builtin_amdgcn_s_setprio(1);
#pragma unroll
    for (int kc = 0; kc < 2; ++kc) {
      s8v pb = *(const s8v*)(Pl[w] + lc * 64 + (((kc * 4 + lg) ^ swz) * 8));
#pragma unroll
      for (int n = 0; n < 4; ++n) {
        s8v vf = *(const s8v*)(Vb_ + (n * 16 + lc) * 64 + (((kc * 4 + lg) ^ swz) * 8));
        acc[n] = mfma16(vf, pb, acc[n]);
      }
    }
    __builtin_amdgcn_s_setprio(0);

    WAITVM0();
    barrier_raw();
    cur ^= 1;
  }
#undef STAGE_KV

  // reduce lsum across the 4 lanes sharing this q (lc, lc+16, lc+32, lc+48)
  lsum += __shfl_xor(lsum, 16);
  lsum += __shfl_xor(lsum, 32);
  const float inv = 1.0f / lsum;
  const int q = q0 + w * 16 + lc;
#pragma unroll
  for (int n = 0; n < 4; ++n) {
    f4v o;
#pragma unroll
    for (int r = 0; r < 4; ++r) o[r] = acc[n][r] * inv;
    *(f4v*)(out + ((size_t)(b * SEQ + q)) * D_DIM + h * 64 + n * 16 + 4 * lg) = o;
  }
}

extern "C" void kernel_launch(void* const* d_in, const int* in_sizes, int n_in,
                              void* d_out, int out_size, void* d_ws, size_t ws_size,
                              hipStream_t stream) {
  const float* x = (const float*)d_in[0];
  const float* Wq = (const float*)d_in[1];
  const float* bq = (const float*)d_in[2];
  const float* Wk = (const float*)d_in[3];
  const float* bk = (const float*)d_in[4];
  const float* Wv = (const float*)d_in[5];
  const float* bv = (const float*)d_in[6];
  const float* Bb = (const float*)d_in[7];
  float* out = (float*)d_out;

  char* ws = (char*)d_ws;
  unsigned short* Xb = (unsigned short*)ws;                          // 8 MiB
  unsigned short* Wb = (unsigned short*)(ws + (8ull << 20));         // 6 MiB
  unsigned short* qb = (unsigned short*)(ws + (14ull << 20));        // 8 MiB
  unsigned short* kb = (unsigned short*)(ws + (22ull << 20));        // 8 MiB
  unsigned short* vt = (unsigned short*)(ws + (30ull << 20));        // 8 MiB

  cvt_all<<<7168, 256, 0, stream>>>(x, Wq, Wk, Wv, Xb, Wb);

  dim3 ggrid(MROWS / 128, D_DIM / 128, 3);
  qkv_gemm<<<ggrid, 256, 0, stream>>>(Xb, Wb, bq, bk, bv, qb, kb, vt);

  dim3 agrid(BSZ * H_NUM, SEQ / 64);
  attn_fwd<<<agrid, 256, 0, stream>>>(qb, kb, vt, Bb, out);
}

// Round 5
// 92.903 us; speedup vs baseline: 1.9448x; 1.1128x over previous
//
#include <hip/hip_runtime.h>
#include <stdint.h>

typedef __attribute__((ext_vector_type(8))) short s8v;
typedef __attribute__((ext_vector_type(4))) short s4v;
typedef __attribute__((ext_vector_type(4))) float f4v;

#define D_DIM 1024
#define H_NUM 16
#define HD 64
#define SEQ 2048
#define BSZ 2
#define MROWS (BSZ * SEQ)   // 4096
#define LOG2E 1.4426950408889634f

__device__ __forceinline__ unsigned short f2bf(float f) {
  unsigned u = __builtin_bit_cast(unsigned, f);
  u += 0x7fffu + ((u >> 16) & 1u);
  return (unsigned short)(u >> 16);
}

__device__ __forceinline__ float exp2q(float x) {
  float r;
  asm("v_exp_f32 %0, %1" : "=v"(r) : "v"(x));
  return r;
}

__device__ __forceinline__ float max3q(float a, float b, float c) {
  float r;
  asm("v_max3_f32 %0, %1, %2, %3" : "=v"(r) : "v"(a), "v"(b), "v"(c));
  return r;
}

__device__ __forceinline__ unsigned int cvtpk(float a, float b) {
  unsigned int r;
  asm("v_cvt_pk_bf16_f32 %0, %1, %2" : "=v"(r) : "v"(a), "v"(b));
  return r;
}

__device__ __forceinline__ void async16(const unsigned short* g, unsigned short* l) {
  __builtin_amdgcn_global_load_lds(
      (__attribute__((address_space(1))) unsigned int*)(uintptr_t)g,
      (__attribute__((address_space(3))) unsigned int*)l, 16, 0, 0);
}

__device__ __forceinline__ f4v mfma16(s8v a, s8v b, f4v c) {
  return __builtin_amdgcn_mfma_f32_16x16x32_bf16(a, b, c, 0, 0, 0);
}

__device__ __forceinline__ void barrier_raw() {
  __builtin_amdgcn_sched_barrier(0);
  __builtin_amdgcn_s_barrier();
  __builtin_amdgcn_sched_barrier(0);
}
#define WAITVM0() asm volatile("s_waitcnt vmcnt(0)" ::: "memory")

// ---------------- fused fp32 -> bf16 convert (x, Wq, Wk, Wv) ----------------
__global__ __launch_bounds__(256) void cvt_all(
    const float* __restrict__ x, const float* __restrict__ Wq,
    const float* __restrict__ Wk, const float* __restrict__ Wv,
    unsigned short* __restrict__ Xb, unsigned short* __restrict__ Wb) {
  const int NX = MROWS * D_DIM / 4;
  const int NW = D_DIM * D_DIM / 4;
  int i = blockIdx.x * 256 + threadIdx.x;
  const float* src;
  unsigned short* dst;
  int off;
  if (i < NX) {
    src = x; dst = Xb; off = i;
  } else if (i < NX + NW) {
    src = Wq; dst = Wb; off = i - NX;
  } else if (i < NX + 2 * NW) {
    src = Wk; dst = Wb + D_DIM * D_DIM; off = i - NX - NW;
  } else {
    src = Wv; dst = Wb + 2 * D_DIM * D_DIM; off = i - NX - 2 * NW;
  }
  f4v v = *(const f4v*)(src + (size_t)off * 4);
  s4v o;
  o[0] = (short)f2bf(v[0]);
  o[1] = (short)f2bf(v[1]);
  o[2] = (short)f2bf(v[2]);
  o[3] = (short)f2bf(v[3]);
  *(s4v*)(dst + (size_t)off * 4) = o;
}

// ---------------- QKV projection GEMM: KSTEP=32, dbuf 2-phase, swizzled ----------------
__global__ __launch_bounds__(256) void qkv_gemm(
    const unsigned short* __restrict__ Xb, const unsigned short* __restrict__ Wb,
    const float* __restrict__ bq, const float* __restrict__ bk,
    const float* __restrict__ bv, unsigned short* __restrict__ qb,
    unsigned short* __restrict__ kb, unsigned short* __restrict__ vt) {
  __shared__ __align__(16) unsigned short At[2][128 * 32];
  __shared__ __align__(16) unsigned short Bt[2][128 * 32];

  const int z = blockIdx.z;
  const unsigned short* W = Wb + z * (D_DIM * D_DIM);
  const float* bias = (z == 0) ? bq : ((z == 1) ? bk : bv);
  const int row0 = blockIdx.x * 128;
  const int col0 = blockIdx.y * 128;
  const int t = threadIdx.x;
  const int w = t >> 6, l = t & 63;
  const int wr = w >> 1, wc = w & 1;
  const int lg = l >> 4, lc = l & 15;

  f4v acc[4][4];
#pragma unroll
  for (int m = 0; m < 4; ++m)
#pragma unroll
    for (int n = 0; n < 4; ++n) acc[m][n] = (f4v){0.f, 0.f, 0.f, 0.f};

  const int srow = t >> 2;
  const int sch = (t & 3) ^ ((t >> 3) & 3);
  const unsigned short* Asrc = Xb + (size_t)(row0 + srow) * D_DIM + sch * 8;
  const unsigned short* Bsrc = W + (size_t)(col0 + srow) * D_DIM + sch * 8;

  const int rch = lg ^ ((lc >> 1) & 3);
  const int arow = wr * 64 + lc;
  const int brow = wc * 64 + lc;

#define STAGE(b, k0)                                                        \
  do {                                                                      \
    async16(Asrc + (k0), At[b] + t * 8);                                    \
    async16(Asrc + (k0) + 64 * D_DIM, At[b] + 2048 + t * 8);                \
    async16(Bsrc + (k0), Bt[b] + t * 8);                                    \
    async16(Bsrc + (k0) + 64 * D_DIM, Bt[b] + 2048 + t * 8);                \
  } while (0)

  STAGE(0, 0);
  WAITVM0();
  barrier_raw();

  int cur = 0;
  for (int it = 0; it < 32; ++it) {
    if (it < 31) STAGE(cur ^ 1, (it + 1) * 32);
    s8v a[4], b[4];
#pragma unroll
    for (int m = 0; m < 4; ++m)
      a[m] = *(const s8v*)(At[cur] + (arow + m * 16) * 32 + rch * 8);
#pragma unroll
    for (int n = 0; n < 4; ++n)
      b[n] = *(const s8v*)(Bt[cur] + (brow + n * 16) * 32 + rch * 8);
    __builtin_amdgcn_s_setprio(1);
#pragma unroll
    for (int m = 0; m < 4; ++m)
#pragma unroll
      for (int n = 0; n < 4; ++n) acc[m][n] = mfma16(a[m], b[n], acc[m][n]);
    __builtin_amdgcn_s_setprio(0);
    WAITVM0();
    barrier_raw();
    cur ^= 1;
  }
#undef STAGE

  const float SCQ = 0.125f * LOG2E;
#pragma unroll
  for (int m = 0; m < 4; ++m) {
    const int sg0 = row0 + wr * 64 + m * 16 + 4 * lg;
    const int b = sg0 >> 11;
    const int sl0 = sg0 & (SEQ - 1);
#pragma unroll
    for (int n = 0; n < 4; ++n) {
      const int j = col0 + wc * 64 + n * 16 + lc;
      const int h = j >> 6, hd = j & 63;
      const float bs = bias[j];
      if (z == 2) {
        s4v o;
#pragma unroll
        for (int r = 0; r < 4; ++r) o[r] = (short)f2bf(acc[m][n][r] + bs);
        *(s4v*)(vt + ((size_t)(b * H_NUM + h) * HD + hd) * SEQ + sl0) = o;
      } else if (z == 0) {
#pragma unroll
        for (int r = 0; r < 4; ++r)
          qb[((size_t)(b * H_NUM + h) * SEQ + (sl0 + r)) * HD + hd] =
              f2bf((acc[m][n][r] + bs) * SCQ);
      } else {
#pragma unroll
        for (int r = 0; r < 4; ++r)
          kb[((size_t)(b * H_NUM + h) * SEQ + (sl0 + r)) * HD + hd] =
              f2bf(acc[m][n][r] + bs);
      }
    }
  }
}

// ---------------- flash attention: 8 waves, QBLK=128, ones-MFMA lsum ----------------
// Q pre-scaled (0.125*log2e), B dropped (key-constant -> softmax-invariant).
// Defer-max THR=8; lsum accumulated via mfma(ones, P^T, lacc) -> every C-row = colsum.
__global__ __launch_bounds__(512, 4) void attn_fwd(
    const unsigned short* __restrict__ qb, const unsigned short* __restrict__ kb,
    const unsigned short* __restrict__ vt, const float* __restrict__ Bb,
    float* __restrict__ out) {
  __shared__ __align__(16) unsigned short Kl[2][64 * 64];
  __shared__ __align__(16) unsigned short Vl[2][64 * 64];
  __shared__ __align__(16) unsigned short Pl[8][16 * 64];

  const int bh = blockIdx.x;
  const int b = bh >> 4, h = bh & 15;
  const int q0 = blockIdx.y * 128;
  const int t = threadIdx.x, w = t >> 6, l = t & 63;
  const int lg = l >> 4, lc = l & 15;
  const int swz = lc & 7;
  (void)Bb;

  const unsigned short* Q = qb + (size_t)bh * SEQ * HD;
  const unsigned short* K = kb + (size_t)bh * SEQ * HD;
  const unsigned short* V = vt + (size_t)bh * HD * SEQ;

  const int qrow = q0 + w * 16 + lc;
  s8v qf0 = *(const s8v*)(Q + (size_t)qrow * HD + 8 * lg);
  s8v qf1 = *(const s8v*)(Q + (size_t)qrow * HD + 32 + 8 * lg);

  s8v ones;
#pragma unroll
  for (int i = 0; i < 8; ++i) ones[i] = (short)0x3F80;   // bf16 1.0

  f4v acc[4];
#pragma unroll
  for (int n = 0; n < 4; ++n) acc[n] = (f4v){0.f, 0.f, 0.f, 0.f};
  f4v lacc = (f4v){0.f, 0.f, 0.f, 0.f};
  float m = -3.0e38f, thr = -3.0e38f;

  // staging: one K chunk + one V chunk per thread per tile (512 thr cover 64x64)
  const int srow = t >> 3;                  // 0..63
  const int sc8 = (t & 7) ^ (srow & 7);     // pre-swizzled source chunk
  const unsigned short* Kst = K + (size_t)srow * HD + sc8 * 8;
  const unsigned short* Vst = V + (size_t)srow * SEQ + sc8 * 8;
  unsigned short* Kd = Kl[0] + t * 8;       // linear dest
  unsigned short* Vd = Vl[0] + t * 8;
  const int ldsw = 64 * 64;

#define STAGE_KV(bsel)                                                      \
  do {                                                                      \
    async16(Kst, Kd + (bsel) * ldsw);                                       \
    async16(Vst, Vd + (bsel) * ldsw);                                       \
    Kst += 64 * HD;                                                         \
    Vst += 64;                                                              \
  } while (0)

  // loop-invariant lane offsets (shorts)
  const int kfo0 = lc * 64 + (lg ^ swz) * 8;
  const int kfo1 = lc * 64 + ((4 + lg) ^ swz) * 8;
  unsigned short* const Pw = Pl[w];
  const unsigned short* pbr0 = Pw + lc * 64 + ((0 + lg) ^ swz) * 8;
  const unsigned short* pbr1 = Pw + lc * 64 + ((4 + lg) ^ swz) * 8;
  unsigned short* pwr[4];
#pragma unroll
  for (int kt4 = 0; kt4 < 4; ++kt4)
    pwr[kt4] = Pw + lc * 64 + (((2 * kt4 + (lg >> 1)) ^ swz) * 8) + 4 * (lg & 1);

  STAGE_KV(0);
  WAITVM0();
  barrier_raw();

  int cur = 0;
  for (int kt = 0; kt < SEQ / 64; ++kt) {
    if (kt < SEQ / 64 - 1) STAGE_KV(cur ^ 1);

    const unsigned short* Kb_ = Kl[cur];
    const unsigned short* Vb_ = Vl[cur];

    // QK^T swapped: lane holds S^T[key=16*kt4+4lg+r][q=lc]
    f4v sv[4];
    __builtin_amdgcn_s_setprio(1);
#pragma unroll
    for (int kt4 = 0; kt4 < 4; ++kt4) {
      s8v kf0 = *(const s8v*)(Kb_ + kfo0 + kt4 * 1024);
      s8v kf1 = *(const s8v*)(Kb_ + kfo1 + kt4 * 1024);
      f4v c = (f4v){0.f, 0.f, 0.f, 0.f};
      c = mfma16(kf0, qf0, c);
      c = mfma16(kf1, qf1, c);
      sv[kt4] = c;
    }
    __builtin_amdgcn_s_setprio(0);

    // lane-local max of 16 via max3
    float t0 = max3q(sv[0][0], sv[0][1], sv[0][2]);
    float t1 = max3q(sv[0][3], sv[1][0], sv[1][1]);
    float t2 = max3q(sv[1][2], sv[1][3], sv[2][0]);
    float t3 = max3q(sv[2][1], sv[2][2], sv[2][3]);
    float t4 = max3q(sv[3][0], sv[3][1], sv[3][2]);
    float tmax = fmaxf(max3q(t0, t1, sv[3][3]), max3q(t2, t3, t4));

    if (!__all(tmax <= thr)) {   // rare: reduce over the q-quad + rescale
      float tr = tmax;
      tr = fmaxf(tr, __shfl_xor(tr, 16));
      tr = fmaxf(tr, __shfl_xor(tr, 32));
      const float mn = fmaxf(m, tr);
      const float fs = exp2q(m - mn);
      m = mn;
      thr = mn + 8.0f;
#pragma unroll
      for (int n = 0; n < 4; ++n)
#pragma unroll
        for (int r = 0; r < 4; ++r) acc[n][r] *= fs;
#pragma unroll
      for (int r = 0; r < 4; ++r) lacc[r] *= fs;
    }

    // p = exp2(s - m); pack to bf16; write P^T
#pragma unroll
    for (int kt4 = 0; kt4 < 4; ++kt4) {
#pragma unroll
      for (int r = 0; r < 4; ++r) sv[kt4][r] = exp2q(sv[kt4][r] - m);
      uint2 dw;
      dw.x = cvtpk(sv[kt4][0], sv[kt4][1]);
      dw.y = cvtpk(sv[kt4][2], sv[kt4][3]);
      *(uint2*)pwr[kt4] = dw;
    }

    // PV: O^T = V^T * P^T ; lsum via ones-row MFMA (every C row = colsum of P)
    __builtin_amdgcn_s_setprio(1);
    {
      s8v pb0 = *(const s8v*)pbr0;
      s8v pb1 = *(const s8v*)pbr1;
      lacc = mfma16(ones, pb0, lacc);
      lacc = mfma16(ones, pb1, lacc);
#pragma unroll
      for (int n = 0; n < 4; ++n) {
        s8v vf0 = *(const s8v*)(Vb_ + kfo0 + n * 1024);   // same lane-offset form
        s8v vf1 = *(const s8v*)(Vb_ + kfo1 + n * 1024);
        acc[n] = mfma16(vf0, pb0, acc[n]);
        acc[n] = mfma16(vf1, pb1, acc[n]);
      }
    }
    __builtin_amdgcn_s_setprio(0);

    WAITVM0();
    barrier_raw();
    cur ^= 1;
  }
#undef STAGE_KV

  // lacc[0] = full sum over keys for q=lc (identical across the lg quad)
  const float inv = 1.0f / lacc[0];
  const int q = q0 + w * 16 + lc;
#pragma unroll
  for (int n = 0; n < 4; ++n) {
    f4v o;
#pragma unroll
    for (int r = 0; r < 4; ++r) o[r] = acc[n][r] * inv;
    *(f4v*)(out + ((size_t)(b * SEQ + q)) * D_DIM + h * 64 + n * 16 + 4 * lg) = o;
  }
}

extern "C" void kernel_launch(void* const* d_in, const int* in_sizes, int n_in,
                              void* d_out, int out_size, void* d_ws, size_t ws_size,
                              hipStream_t stream) {
  const float* x = (const float*)d_in[0];
  const float* Wq = (const float*)d_in[1];
  const float* bq = (const float*)d_in[2];
  const float* Wk = (const float*)d_in[3];
  const float* bk = (const float*)d_in[4];
  const float* Wv = (const float*)d_in[5];
  const float* bv = (const float*)d_in[6];
  const float* Bb = (const float*)d_in[7];
  float* out = (float*)d_out;

  char* ws = (char*)d_ws;
  unsigned short* Xb = (unsigned short*)ws;                          // 8 MiB
  unsigned short* Wb = (unsigned short*)(ws + (8ull << 20));         // 6 MiB
  unsigned short* qb = (unsigned short*)(ws + (14ull << 20));        // 8 MiB
  unsigned short* kb = (unsigned short*)(ws + (22ull << 20));        // 8 MiB
  unsigned short* vt = (unsigned short*)(ws + (30ull << 20));        // 8 MiB

  cvt_all<<<7168, 256, 0, stream>>>(x, Wq, Wk, Wv, Xb, Wb);

  dim3 ggrid(MROWS / 128, D_DIM / 128, 3);
  qkv_gemm<<<ggrid, 256, 0, stream>>>(Xb, Wb, bq, bk, bv, qb, kb, vt);

  dim3 agrid(BSZ * H_NUM, SEQ / 128);
  attn_fwd<<<agrid, 512, 0, stream>>>(qb, kb, vt, Bb, out);
}